// Round 10
// baseline (632.357 us; speedup 1.0000x reference)
//
#include <hip/hip_runtime.h>
#include <hip/hip_fp16.h>
#include <hip/hip_cooperative_groups.h>

namespace cg = cooperative_groups;

#define N_NODES 50000
#define N_EDGES 600000
#define N_GRAPHS 64
#define HID 128
#define OUT_C 32

#define COOP_BLOCKS 512

typedef __attribute__((ext_vector_type(8))) _Float16 half8;
typedef __attribute__((ext_vector_type(4))) _Float16 half4;
typedef __attribute__((ext_vector_type(4))) float f32x4;

// ================= cooperative prep + CSR build (replaces 8 dispatches) =================
// P0 zero + fp16 casts -> P1 degree atomics -> P2 3-step rowptr scan -> P3 fill
__global__ __launch_bounds__(256, 2) void coop_prep_csr(
    const float* __restrict__ x,
    const float* __restrict__ W1l, const float* __restrict__ W1r,
    const float* __restrict__ W2l, const float* __restrict__ W2r,
    const int* __restrict__ src, const int* __restrict__ dst,
    __half* __restrict__ xh, __half* __restrict__ Wt1, __half* __restrict__ Wt2,
    int* __restrict__ degi, int* __restrict__ cursor, int* __restrict__ rowptr,
    int* __restrict__ eidx, float* __restrict__ invdeg,
    int* __restrict__ bsum, int* __restrict__ boff, int* __restrict__ done) {
    cg::grid_group grid = cg::this_grid();
    const int t = threadIdx.x;
    const int b = blockIdx.x;
    const int gtid = b * 256 + t;
    const int gstride = COOP_BLOCKS * 256;
    __shared__ int s[256];

    // ---- P0: zero counters + cast weights (n-major fp16) + cast x
    for (int i = gtid; i < N_NODES; i += gstride) { degi[i] = 0; cursor[i] = 0; }
    if (gtid == 0) *done = 0;
    for (int i = gtid; i < 65536; i += gstride) {
        int which = i >> 15;                    // 0: layer1, 1: layer2
        int j = i & 32767;
        int n = j >> 8, k = j & 255;
        const float* Wl = which ? W2l : W1l;
        const float* Wr = which ? W2r : W1r;
        float a = (k < 128) ? Wl[n * 128 + k] : Wr[n * 128 + (k - 128)];
        (which ? Wt2 : Wt1)[j] = __float2half(a);
    }
    for (int i = gtid * 4; i < N_NODES * 128; i += gstride * 4) {
        float4 v = *(const float4*)(x + i);
        __half2 a = __floats2half2_rn(v.x, v.y);
        __half2 c = __floats2half2_rn(v.z, v.w);
        uint2 st;
        st.x = *(const unsigned int*)&a;
        st.y = *(const unsigned int*)&c;
        *(uint2*)(xh + i) = st;
    }
    grid.sync();

    // ---- P1: degrees
    for (int e = gtid; e < N_EDGES; e += gstride) atomicAdd(&degi[dst[e]], 1);
    grid.sync();

    // ---- P2a: block-local exclusive scan of its node chunk
    const int npb = (N_NODES + COOP_BLOCKS - 1) / COOP_BLOCKS;   // 98 (<= 256)
    const int base = b * npb;
    const int idx = base + t;
    int v = 0;
    if (t < npb && idx < N_NODES) v = degi[idx];
    s[t] = v;
    __syncthreads();
    for (int off = 1; off < 256; off <<= 1) {
        int u = (t >= off) ? s[t - off] : 0;
        __syncthreads();
        s[t] += u;
        __syncthreads();
    }
    int incl = s[t];
    if (t == 255) bsum[b] = incl;
    if (t < npb && idx < N_NODES) rowptr[idx] = incl - v;   // local exclusive
    grid.sync();

    // ---- P2b: block 0 exclusive-scans the 512 block sums
    if (b == 0) {
        int v0 = bsum[2 * t], v1 = bsum[2 * t + 1];
        s[t] = v0 + v1;
        __syncthreads();
        for (int off = 1; off < 256; off <<= 1) {
            int u = (t >= off) ? s[t - off] : 0;
            __syncthreads();
            s[t] += u;
            __syncthreads();
        }
        int excl = s[t] - (v0 + v1);
        boff[2 * t] = excl;
        boff[2 * t + 1] = excl + v0;
        if (t == 255) rowptr[N_NODES] = s[t];
    }
    grid.sync();

    // ---- P2c: add block offset; emit invdeg
    {
        int bo = boff[b];
        if (t < npb && idx < N_NODES) {
            rowptr[idx] += bo;
            invdeg[idx] = 1.0f / fmaxf((float)v, 1.0f);
        }
    }
    grid.sync();

    // ---- P3: fill CSR
    for (int e = gtid; e < N_EDGES; e += gstride) {
        int d = dst[e];
        int pos = atomicAdd(&cursor[d], 1);
        eidx[rowptr[d] + pos] = src[e];
    }
}

// ================= fp16 gather-aggregate: 2 nodes per wave, 32 lanes x 8 B =================
#define AGG_ACC(vv, aa) { aa.x += (float)vv[0]; aa.y += (float)vv[1]; \
                          aa.z += (float)vv[2]; aa.w += (float)vv[3]; }

__global__ __launch_bounds__(256) void aggregate_f16(
    const __half* __restrict__ feat16, const int* __restrict__ rowptr,
    const int* __restrict__ eidx, const float* __restrict__ invdeg,
    __half* __restrict__ mean16) {
    const int wave = threadIdx.x >> 6;
    const int lane = threadIdx.x & 63;
    const int nh   = lane >> 5;
    const int sub  = lane & 31;
    const int node = blockIdx.x * 8 + wave * 2 + nh;
    const bool act = (node < N_NODES);
    int beg = 0, end = 0;
    if (act) { beg = rowptr[node]; end = rowptr[node + 1]; }
    const size_t coff = (size_t)sub * 4;

    float4 a0 = {0.f,0.f,0.f,0.f}, a1 = {0.f,0.f,0.f,0.f};
    float4 a2 = {0.f,0.f,0.f,0.f}, a3 = {0.f,0.f,0.f,0.f};
    int i = beg;
    for (; i + 8 <= end; i += 8) {
        int s0 = eidx[i+0], s1 = eidx[i+1], s2 = eidx[i+2], s3 = eidx[i+3];
        int s4 = eidx[i+4], s5 = eidx[i+5], s6 = eidx[i+6], s7 = eidx[i+7];
        half4 v0 = *(const half4*)(feat16 + (size_t)s0 * 128 + coff);
        half4 v1 = *(const half4*)(feat16 + (size_t)s1 * 128 + coff);
        half4 v2 = *(const half4*)(feat16 + (size_t)s2 * 128 + coff);
        half4 v3 = *(const half4*)(feat16 + (size_t)s3 * 128 + coff);
        half4 v4 = *(const half4*)(feat16 + (size_t)s4 * 128 + coff);
        half4 v5 = *(const half4*)(feat16 + (size_t)s5 * 128 + coff);
        half4 v6 = *(const half4*)(feat16 + (size_t)s6 * 128 + coff);
        half4 v7 = *(const half4*)(feat16 + (size_t)s7 * 128 + coff);
        AGG_ACC(v0, a0); AGG_ACC(v1, a1); AGG_ACC(v2, a2); AGG_ACC(v3, a3);
        AGG_ACC(v4, a0); AGG_ACC(v5, a1); AGG_ACC(v6, a2); AGG_ACC(v7, a3);
    }
    if (i + 4 <= end) {
        int s0 = eidx[i+0], s1 = eidx[i+1], s2 = eidx[i+2], s3 = eidx[i+3];
        half4 v0 = *(const half4*)(feat16 + (size_t)s0 * 128 + coff);
        half4 v1 = *(const half4*)(feat16 + (size_t)s1 * 128 + coff);
        half4 v2 = *(const half4*)(feat16 + (size_t)s2 * 128 + coff);
        half4 v3 = *(const half4*)(feat16 + (size_t)s3 * 128 + coff);
        AGG_ACC(v0, a0); AGG_ACC(v1, a1); AGG_ACC(v2, a2); AGG_ACC(v3, a3);
        i += 4;
    }
    if (i + 2 <= end) {
        int s0 = eidx[i+0], s1 = eidx[i+1];
        half4 v0 = *(const half4*)(feat16 + (size_t)s0 * 128 + coff);
        half4 v1 = *(const half4*)(feat16 + (size_t)s1 * 128 + coff);
        AGG_ACC(v0, a0); AGG_ACC(v1, a1);
        i += 2;
    }
    if (i < end) {
        int s0 = eidx[i];
        half4 v0 = *(const half4*)(feat16 + (size_t)s0 * 128 + coff);
        AGG_ACC(v0, a0);
    }

    if (act) {
        const float sc = invdeg[node];
        half4 r;
        r[0] = (_Float16)(((a0.x + a1.x) + (a2.x + a3.x)) * sc);
        r[1] = (_Float16)(((a0.y + a1.y) + (a2.y + a3.y)) * sc);
        r[2] = (_Float16)(((a0.z + a1.z) + (a2.z + a3.z)) * sc);
        r[3] = (_Float16)(((a0.w + a1.w) + (a2.w + a3.w)) * sc);
        *(half4*)(mean16 + (size_t)node * 128 + coff) = r;
    }
}

// ================= fp16 MFMA SAGE GEMM (M=50000, N=128, K=256) =================
#define GBM 64
#define BPAD 8

__global__ __launch_bounds__(256) void sage_gemm_f16(
    const __half* __restrict__ mean16, const __half* __restrict__ feat16,
    const __half* __restrict__ Wt, const float* __restrict__ bias,
    __half* __restrict__ out16, int M) {
    __shared__ __align__(16) __half Bs[128][256 + BPAD];

    const int tid = threadIdx.x;
    const int wave = tid >> 6;
    const int lane = tid & 63;
    const int l15 = lane & 15;
    const int quad = lane >> 4;
    const int row0 = blockIdx.x * GBM;
    const int gi_a = min(row0 + wave * 16 + l15, M - 1);   // clamp OOB (stores guarded)

    for (int id = tid; id < 128 * 32; id += 256) {
        int n = id >> 5;
        int kc = (id & 31) * 8;
        *(half8*)&Bs[n][kc] = *(const half8*)(Wt + (size_t)n * 256 + kc);
    }

    half8 af[8];
#pragma unroll
    for (int kb = 0; kb < 8; ++kb) {
        const int k0 = kb * 32;
        const __half* ap = (k0 < 128)
            ? (mean16 + (size_t)gi_a * 128 + k0 + quad * 8)
            : (feat16 + (size_t)gi_a * 128 + (k0 - 128) + quad * 8);
        af[kb] = *(const half8*)ap;
    }

    f32x4 acc[8];
#pragma unroll
    for (int t = 0; t < 8; ++t) acc[t] = (f32x4){0.f, 0.f, 0.f, 0.f};

    __syncthreads();

#pragma unroll
    for (int kb = 0; kb < 8; ++kb) {
#pragma unroll
        for (int t = 0; t < 8; ++t) {
            const half8 b = *(const half8*)&Bs[t * 16 + l15][kb * 32 + quad * 8];
            acc[t] = __builtin_amdgcn_mfma_f32_16x16x32_f16(af[kb], b, acc[t], 0, 0, 0);
        }
    }

#pragma unroll
    for (int r = 0; r < 4; ++r) {
        int gi = row0 + wave * 16 + quad * 4 + r;
        if (gi < M) {
#pragma unroll
            for (int t = 0; t < 8; ++t) {
                int col = t * 16 + l15;
                float v = fmaxf(acc[t][r] + bias[col], 0.f);
                out16[(size_t)gi * 128 + col] = __float2half(v);
            }
        }
    }
}

// ================= fused pool + final linear (last-block reduction) =================
#define POOL_PARTS 4
__global__ __launch_bounds__(256) void pool_final(
    const __half* __restrict__ h, const int* __restrict__ batch,
    const float* __restrict__ Wlin, const float* __restrict__ blin,
    float* __restrict__ pooled_parts, int* __restrict__ gcnt,
    int* __restrict__ done, float* __restrict__ out) {
    const int g = blockIdx.x >> 2;
    const int part = blockIdx.x & 3;
    int lo = 0, hi = N_NODES;
    while (lo < hi) { int mid = (lo + hi) >> 1; if (batch[mid] < g) lo = mid + 1; else hi = mid; }
    const int start = lo;
    hi = N_NODES;
    while (lo < hi) { int mid = (lo + hi) >> 1; if (batch[mid] < g + 1) lo = mid + 1; else hi = mid; }
    const int end = lo;

    const int t = threadIdx.x;
    if (part == 0 && t == 0) gcnt[g] = end - start;

    const int c4 = (t & 31) * 4;
    const int rg = t >> 5;
    float4 acc = {0.f, 0.f, 0.f, 0.f};
    for (int n = start + part * 8 + rg; n < end; n += 8 * POOL_PARTS) {
        const __half2* p = (const __half2*)(h + (size_t)n * 128 + c4);
        float2 f0 = __half22float2(p[0]);
        float2 f1 = __half22float2(p[1]);
        acc.x += f0.x; acc.y += f0.y; acc.z += f1.x; acc.w += f1.y;
    }
    __shared__ float sm[8][132];
    sm[rg][c4 + 0] = acc.x;
    sm[rg][c4 + 1] = acc.y;
    sm[rg][c4 + 2] = acc.z;
    sm[rg][c4 + 3] = acc.w;
    __syncthreads();
    if (t < 128) {
        float s = 0.f;
#pragma unroll
        for (int r = 0; r < 8; ++r) s += sm[r][t];
        pooled_parts[(size_t)blockIdx.x * 128 + t] = s;
    }

    // last-block election
    __threadfence();
    __shared__ int lastflag;
    if (t == 0) {
        int old = atomicAdd(done, 1);
        lastflag = (old == (int)gridDim.x - 1);
    }
    __syncthreads();
    if (!lastflag) return;
    __threadfence();

    for (int task = t; task < N_GRAPHS * OUT_C; task += 256) {
        int gg = task >> 5;
        int j = task & 31;
        float inv = 1.0f / fmaxf((float)gcnt[gg], 1.0f);
        float sum = blin[j];
        const float* w = Wlin + j * 128;
        const float* p0 = pooled_parts + (size_t)(gg * 4 + 0) * 128;
        const float* p1 = pooled_parts + (size_t)(gg * 4 + 1) * 128;
        const float* p2 = pooled_parts + (size_t)(gg * 4 + 2) * 128;
        const float* p3 = pooled_parts + (size_t)(gg * 4 + 3) * 128;
        for (int c = 0; c < 128; ++c) {
            float p = (p0[c] + p1[c]) + (p2[c] + p3[c]);
            sum += p * inv * w[c];
        }
        out[task] = sum;
    }
}

extern "C" void kernel_launch(void* const* d_in, const int* in_sizes, int n_in,
                              void* d_out, int out_size, void* d_ws, size_t ws_size,
                              hipStream_t stream) {
    const float* x    = (const float*)d_in[0];
    const int*   src  = (const int*)d_in[1];
    const int*   dst  = ((const int*)d_in[1]) + N_EDGES;
    const int*   batch= (const int*)d_in[2];
    const float* W1l  = (const float*)d_in[3];
    const float* b1   = (const float*)d_in[4];
    const float* W1r  = (const float*)d_in[5];
    const float* W2l  = (const float*)d_in[6];
    const float* b2   = (const float*)d_in[7];
    const float* W2r  = (const float*)d_in[8];
    const float* Wlin = (const float*)d_in[9];
    const float* blin = (const float*)d_in[10];
    float* out = (float*)d_out;

    __half* xh     = (__half*)d_ws;                 // 6,400,000 h
    __half* mean16 = xh + 6400000;                  // 6,400,000 h
    __half* h1_16  = mean16 + 6400000;              // 6,400,000 h
    __half* h2_16  = h1_16 + 6400000;               // 6,400,000 h
    __half* Wt1    = h2_16 + 6400000;               // 32,768 h
    __half* Wt2    = Wt1 + 32768;                   // 32,768 h
    float* pooled_parts = (float*)(Wt2 + 32768);    // 32,768 f (256 blocks x 128)
    float* invdeg  = pooled_parts + 32768;          // 50,000 f
    int*   gcnt    = (int*)(invdeg + N_NODES);      // 64 i
    int*   done    = gcnt + 64;                     // 1 i
    int*   degi    = done + 1;                      // 50,000 i
    int*   cursor  = degi + N_NODES;                // 50,000 i
    int*   rowptr  = cursor + N_NODES;              // 50,001 i
    int*   eidx    = rowptr + N_NODES + 1;          // 600,000 i
    int*   bsum    = eidx + N_EDGES;                // 512 i
    int*   boff    = bsum + COOP_BLOCKS;            // 512 i

    // ---- 1 cooperative dispatch: prep (casts) + CSR build (zero/deg/scan/fill)
    void* cargs[] = {
        (void*)&x, (void*)&W1l, (void*)&W1r, (void*)&W2l, (void*)&W2r,
        (void*)&src, (void*)&dst,
        (void*)&xh, (void*)&Wt1, (void*)&Wt2,
        (void*)&degi, (void*)&cursor, (void*)&rowptr, (void*)&eidx,
        (void*)&invdeg, (void*)&bsum, (void*)&boff, (void*)&done
    };
    hipLaunchCooperativeKernel((void*)coop_prep_csr, dim3(COOP_BLOCKS), dim3(256),
                               cargs, 0, stream);

    const int gemm_grid = (N_NODES + GBM - 1) / GBM;   // 782
    const int agg_grid = (N_NODES + 7) / 8;            // 6250

    // layer 1
    aggregate_f16<<<agg_grid, 256, 0, stream>>>(xh, rowptr, eidx, invdeg, mean16);
    sage_gemm_f16<<<gemm_grid, 256, 0, stream>>>(mean16, xh, Wt1, b1, h1_16, N_NODES);

    // layer 2
    aggregate_f16<<<agg_grid, 256, 0, stream>>>(h1_16, rowptr, eidx, invdeg, mean16);
    sage_gemm_f16<<<gemm_grid, 256, 0, stream>>>(mean16, h1_16, Wt2, b2, h2_16, N_NODES);

    // fused pool + final
    pool_final<<<N_GRAPHS * POOL_PARTS, 256, 0, stream>>>(
        h2_16, batch, Wlin, blin, pooled_parts, gcnt, done, out);
}

// Round 11
// 331.661 us; speedup vs baseline: 1.9066x; 1.9066x over previous
//
#include <hip/hip_runtime.h>
#include <hip/hip_fp16.h>

#define N_NODES 50000
#define N_EDGES 600000
#define N_GRAPHS 64
#define HID 128
#define OUT_C 32

#define N_SCAN_BLOCKS ((N_NODES + 255) / 256)   // 196
#define SCAN_FLAG 0x40000000

typedef __attribute__((ext_vector_type(8))) _Float16 half8;
typedef __attribute__((ext_vector_type(4))) float f32x4;

// ================= prep: zero counters + fp16 weight/x casts (absorbs all memsets) ==========
// zero region layout (contiguous ints): degi[50000] cursor[50000] bsum[196] done[1]
#define ZERO_INTS (2 * N_NODES + N_SCAN_BLOCKS + 1)

__global__ __launch_bounds__(256) void prep_kernel(
    const float* __restrict__ x,
    const float* __restrict__ W1l, const float* __restrict__ W1r,
    const float* __restrict__ W2l, const float* __restrict__ W2r,
    __half* __restrict__ xh, __half* __restrict__ Wt1, __half* __restrict__ Wt2,
    int* __restrict__ zero_base) {
    const int b = blockIdx.x;
    const int t = threadIdx.x;
    const int gtid = b * 256 + t;
    const int gsz = gridDim.x * 256;
    for (int i = gtid; i < ZERO_INTS; i += gsz) zero_base[i] = 0;

    if (b < 16) {
        for (int i = gtid; i < 65536; i += 4096) {
            int which = i >> 15;                    // 0: layer1, 1: layer2
            int j = i & 32767;
            int n = j >> 8, k = j & 255;
            const float* Wl = which ? W2l : W1l;
            const float* Wr = which ? W2r : W1r;
            float a = (k < 128) ? Wl[n * 128 + k] : Wr[n * 128 + (k - 128)];
            (which ? Wt2 : Wt1)[j] = __float2half(a);
        }
    } else {
        int i = ((b - 16) * 256 + t) * 4;
        if (i < N_NODES * 128) {
            float4 v = *(const float4*)(x + i);
            __half2 a = __floats2half2_rn(v.x, v.y);
            __half2 c = __floats2half2_rn(v.z, v.w);
            uint2 st;
            st.x = *(const unsigned int*)&a;
            st.y = *(const unsigned int*)&c;
            *(uint2*)(xh + i) = st;
        }
    }
}

// ================= CSR: degrees =================
__global__ void deg_kernel(const int* __restrict__ dst, int* __restrict__ deg, int E) {
    int e = blockIdx.x * 256 + threadIdx.x;
    if (e < E) atomicAdd(&deg[dst[e]], 1);
}

// ================= CSR: single-dispatch scan (decoupled lookback) =================
// 196 blocks, all co-resident (<= 256 CUs). No grid-wide barrier: each block
// publishes its chunk total as (val | SCAN_FLAG) in one atomic word; block b's
// thread t spins on predecessor t's word, LDS-reduces the offsets.
__global__ __launch_bounds__(256) void scan_fused(
    const int* __restrict__ deg, int* __restrict__ bsum,
    int* __restrict__ rowptr, float* __restrict__ invdeg) {
    __shared__ int s[256];
    const int b = blockIdx.x;
    const int t = threadIdx.x;
    const int idx = b * 256 + t;
    const int v = (idx < N_NODES) ? deg[idx] : 0;
    s[t] = v;
    __syncthreads();
    for (int off = 1; off < 256; off <<= 1) {
        int u = (t >= off) ? s[t - off] : 0;
        __syncthreads();
        s[t] += u;
        __syncthreads();
    }
    const int incl = s[t];
    if (t == 255) atomicExch(&bsum[b], incl | SCAN_FLAG);

    int pv = 0;
    if (t < b) {
        int w;
        do { w = atomicAdd(&bsum[t], 0); } while (!(w & SCAN_FLAG));
        pv = w & ~SCAN_FLAG;
    }
    __syncthreads();
    s[t] = pv;
    __syncthreads();
    for (int off = 128; off > 0; off >>= 1) {
        if (t < off) s[t] += s[t + off];
        __syncthreads();
    }
    const int boffs = s[0];

    if (idx < N_NODES) {
        rowptr[idx] = boffs + incl - v;
        invdeg[idx] = 1.0f / fmaxf((float)v, 1.0f);
    }
    if (b == N_SCAN_BLOCKS - 1 && t == 255) rowptr[N_NODES] = boffs + incl;
}

// ================= CSR: fill =================
__global__ void fill_kernel(const int* __restrict__ src, const int* __restrict__ dst,
                            const int* __restrict__ rowptr, int* __restrict__ cursor,
                            int* __restrict__ eidx, int E) {
    int e = blockIdx.x * 256 + threadIdx.x;
    if (e < E) {
        int d = dst[e];
        int pos = atomicAdd(&cursor[d], 1);
        eidx[rowptr[d] + pos] = src[e];
    }
}

// ================= fp16 gather-aggregate: 4 nodes per wave, 16 lanes x 16 B =================
#define AGG8(vv, aa, ab) { aa.x += (float)vv[0]; aa.y += (float)vv[1]; \
                           aa.z += (float)vv[2]; aa.w += (float)vv[3]; \
                           ab.x += (float)vv[4]; ab.y += (float)vv[5]; \
                           ab.z += (float)vv[6]; ab.w += (float)vv[7]; }

__global__ __launch_bounds__(256) void aggregate_f16(
    const __half* __restrict__ feat16, const int* __restrict__ rowptr,
    const int* __restrict__ eidx, const float* __restrict__ invdeg,
    __half* __restrict__ mean16) {
    const int wave = threadIdx.x >> 6;
    const int lane = threadIdx.x & 63;
    const int nh   = lane >> 4;          // which of the wave's 4 nodes
    const int sub  = lane & 15;          // 16 lanes x 8 halfs = 128 ch
    const int node = blockIdx.x * 16 + wave * 4 + nh;
    const bool act = (node < N_NODES);
    int beg = 0, end = 0;
    if (act) { beg = rowptr[node]; end = rowptr[node + 1]; }
    const size_t coff = (size_t)sub * 8;

    float4 a0 = {0.f,0.f,0.f,0.f}, b0 = {0.f,0.f,0.f,0.f};
    float4 a1 = {0.f,0.f,0.f,0.f}, b1 = {0.f,0.f,0.f,0.f};
    float4 a2 = {0.f,0.f,0.f,0.f}, b2 = {0.f,0.f,0.f,0.f};
    float4 a3 = {0.f,0.f,0.f,0.f}, b3 = {0.f,0.f,0.f,0.f};
    int i = beg;
    for (; i + 8 <= end; i += 8) {
        int s0 = eidx[i+0], s1 = eidx[i+1], s2 = eidx[i+2], s3 = eidx[i+3];
        int s4 = eidx[i+4], s5 = eidx[i+5], s6 = eidx[i+6], s7 = eidx[i+7];
        half8 v0 = *(const half8*)(feat16 + (size_t)s0 * 128 + coff);
        half8 v1 = *(const half8*)(feat16 + (size_t)s1 * 128 + coff);
        half8 v2 = *(const half8*)(feat16 + (size_t)s2 * 128 + coff);
        half8 v3 = *(const half8*)(feat16 + (size_t)s3 * 128 + coff);
        half8 v4 = *(const half8*)(feat16 + (size_t)s4 * 128 + coff);
        half8 v5 = *(const half8*)(feat16 + (size_t)s5 * 128 + coff);
        half8 v6 = *(const half8*)(feat16 + (size_t)s6 * 128 + coff);
        half8 v7 = *(const half8*)(feat16 + (size_t)s7 * 128 + coff);
        AGG8(v0, a0, b0); AGG8(v1, a1, b1); AGG8(v2, a2, b2); AGG8(v3, a3, b3);
        AGG8(v4, a0, b0); AGG8(v5, a1, b1); AGG8(v6, a2, b2); AGG8(v7, a3, b3);
    }
    if (i + 4 <= end) {
        int s0 = eidx[i+0], s1 = eidx[i+1], s2 = eidx[i+2], s3 = eidx[i+3];
        half8 v0 = *(const half8*)(feat16 + (size_t)s0 * 128 + coff);
        half8 v1 = *(const half8*)(feat16 + (size_t)s1 * 128 + coff);
        half8 v2 = *(const half8*)(feat16 + (size_t)s2 * 128 + coff);
        half8 v3 = *(const half8*)(feat16 + (size_t)s3 * 128 + coff);
        AGG8(v0, a0, b0); AGG8(v1, a1, b1); AGG8(v2, a2, b2); AGG8(v3, a3, b3);
        i += 4;
    }
    if (i + 2 <= end) {
        int s0 = eidx[i+0], s1 = eidx[i+1];
        half8 v0 = *(const half8*)(feat16 + (size_t)s0 * 128 + coff);
        half8 v1 = *(const half8*)(feat16 + (size_t)s1 * 128 + coff);
        AGG8(v0, a0, b0); AGG8(v1, a1, b1);
        i += 2;
    }
    if (i < end) {
        int s0 = eidx[i];
        half8 v0 = *(const half8*)(feat16 + (size_t)s0 * 128 + coff);
        AGG8(v0, a0, b0);
    }

    if (act) {
        const float sc = invdeg[node];
        half8 r;
        r[0] = (_Float16)(((a0.x + a1.x) + (a2.x + a3.x)) * sc);
        r[1] = (_Float16)(((a0.y + a1.y) + (a2.y + a3.y)) * sc);
        r[2] = (_Float16)(((a0.z + a1.z) + (a2.z + a3.z)) * sc);
        r[3] = (_Float16)(((a0.w + a1.w) + (a2.w + a3.w)) * sc);
        r[4] = (_Float16)(((b0.x + b1.x) + (b2.x + b3.x)) * sc);
        r[5] = (_Float16)(((b0.y + b1.y) + (b2.y + b3.y)) * sc);
        r[6] = (_Float16)(((b0.z + b1.z) + (b2.z + b3.z)) * sc);
        r[7] = (_Float16)(((b0.w + b1.w) + (b2.w + b3.w)) * sc);
        *(half8*)(mean16 + (size_t)node * 128 + coff) = r;
    }
}

// ================= fp16 MFMA SAGE GEMM (M=50000, N=128, K=256) =================
#define GBM 64
#define BPAD 8

__global__ __launch_bounds__(256) void sage_gemm_f16(
    const __half* __restrict__ mean16, const __half* __restrict__ feat16,
    const __half* __restrict__ Wt, const float* __restrict__ bias,
    __half* __restrict__ out16, int M) {
    __shared__ __align__(16) __half Bs[128][256 + BPAD];

    const int tid = threadIdx.x;
    const int wave = tid >> 6;
    const int lane = tid & 63;
    const int l15 = lane & 15;
    const int quad = lane >> 4;
    const int row0 = blockIdx.x * GBM;
    const int gi_a = min(row0 + wave * 16 + l15, M - 1);

    for (int id = tid; id < 128 * 32; id += 256) {
        int n = id >> 5;
        int kc = (id & 31) * 8;
        *(half8*)&Bs[n][kc] = *(const half8*)(Wt + (size_t)n * 256 + kc);
    }

    half8 af[8];
#pragma unroll
    for (int kb = 0; kb < 8; ++kb) {
        const int k0 = kb * 32;
        const __half* ap = (k0 < 128)
            ? (mean16 + (size_t)gi_a * 128 + k0 + quad * 8)
            : (feat16 + (size_t)gi_a * 128 + (k0 - 128) + quad * 8);
        af[kb] = *(const half8*)ap;
    }

    f32x4 acc[8];
#pragma unroll
    for (int t = 0; t < 8; ++t) acc[t] = (f32x4){0.f, 0.f, 0.f, 0.f};

    __syncthreads();

#pragma unroll
    for (int kb = 0; kb < 8; ++kb) {
#pragma unroll
        for (int t = 0; t < 8; ++t) {
            const half8 b = *(const half8*)&Bs[t * 16 + l15][kb * 32 + quad * 8];
            acc[t] = __builtin_amdgcn_mfma_f32_16x16x32_f16(af[kb], b, acc[t], 0, 0, 0);
        }
    }

#pragma unroll
    for (int r = 0; r < 4; ++r) {
        int gi = row0 + wave * 16 + quad * 4 + r;
        if (gi < M) {
#pragma unroll
            for (int t = 0; t < 8; ++t) {
                int col = t * 16 + l15;
                float v = fmaxf(acc[t][r] + bias[col], 0.f);
                out16[(size_t)gi * 128 + col] = __float2half(v);
            }
        }
    }
}

// ================= fused pool + final linear (last-block election, no grid sync) ==========
#define POOL_PARTS 4
__global__ __launch_bounds__(256) void pool_final(
    const __half* __restrict__ h, const int* __restrict__ batch,
    const float* __restrict__ Wlin, const float* __restrict__ blin,
    float* __restrict__ pooled_parts, int* __restrict__ gcnt,
    int* __restrict__ done, float* __restrict__ out) {
    const int g = blockIdx.x >> 2;
    const int part = blockIdx.x & 3;
    int lo = 0, hi = N_NODES;
    while (lo < hi) { int mid = (lo + hi) >> 1; if (batch[mid] < g) lo = mid + 1; else hi = mid; }
    const int start = lo;
    hi = N_NODES;
    while (lo < hi) { int mid = (lo + hi) >> 1; if (batch[mid] < g + 1) lo = mid + 1; else hi = mid; }
    const int end = lo;

    const int t = threadIdx.x;
    if (part == 0 && t == 0) gcnt[g] = end - start;

    const int c4 = (t & 31) * 4;
    const int rg = t >> 5;
    float4 acc = {0.f, 0.f, 0.f, 0.f};
    for (int n = start + part * 8 + rg; n < end; n += 8 * POOL_PARTS) {
        const __half2* p = (const __half2*)(h + (size_t)n * 128 + c4);
        float2 f0 = __half22float2(p[0]);
        float2 f1 = __half22float2(p[1]);
        acc.x += f0.x; acc.y += f0.y; acc.z += f1.x; acc.w += f1.y;
    }
    __shared__ float sm[8][132];
    sm[rg][c4 + 0] = acc.x;
    sm[rg][c4 + 1] = acc.y;
    sm[rg][c4 + 2] = acc.z;
    sm[rg][c4 + 3] = acc.w;
    __syncthreads();
    if (t < 128) {
        float s = 0.f;
#pragma unroll
        for (int r = 0; r < 8; ++r) s += sm[r][t];
        pooled_parts[(size_t)blockIdx.x * 128 + t] = s;
    }

    __threadfence();
    __shared__ int lastflag;
    if (t == 0) {
        int old = atomicAdd(done, 1);
        lastflag = (old == (int)gridDim.x - 1);
    }
    __syncthreads();
    if (!lastflag) return;
    __threadfence();

    for (int task = t; task < N_GRAPHS * OUT_C; task += 256) {
        int gg = task >> 5;
        int j = task & 31;
        float inv = 1.0f / fmaxf((float)gcnt[gg], 1.0f);
        float sum = blin[j];
        const float* w = Wlin + j * 128;
        const float* p0 = pooled_parts + (size_t)(gg * 4 + 0) * 128;
        const float* p1 = pooled_parts + (size_t)(gg * 4 + 1) * 128;
        const float* p2 = pooled_parts + (size_t)(gg * 4 + 2) * 128;
        const float* p3 = pooled_parts + (size_t)(gg * 4 + 3) * 128;
        for (int c = 0; c < 128; ++c) {
            float p = (p0[c] + p1[c]) + (p2[c] + p3[c]);
            sum += p * inv * w[c];
        }
        out[task] = sum;
    }
}

extern "C" void kernel_launch(void* const* d_in, const int* in_sizes, int n_in,
                              void* d_out, int out_size, void* d_ws, size_t ws_size,
                              hipStream_t stream) {
    const float* x    = (const float*)d_in[0];
    const int*   src  = (const int*)d_in[1];
    const int*   dst  = ((const int*)d_in[1]) + N_EDGES;
    const int*   batch= (const int*)d_in[2];
    const float* W1l  = (const float*)d_in[3];
    const float* b1   = (const float*)d_in[4];
    const float* W1r  = (const float*)d_in[5];
    const float* W2l  = (const float*)d_in[6];
    const float* b2   = (const float*)d_in[7];
    const float* W2r  = (const float*)d_in[8];
    const float* Wlin = (const float*)d_in[9];
    const float* blin = (const float*)d_in[10];
    float* out = (float*)d_out;

    __half* xh     = (__half*)d_ws;                 // 6,400,000 h
    __half* mean16 = xh + 6400000;                  // 6,400,000 h
    __half* h1_16  = mean16 + 6400000;              // 6,400,000 h
    __half* h2_16  = h1_16 + 6400000;               // 6,400,000 h
    __half* Wt1    = h2_16 + 6400000;               // 32,768 h
    __half* Wt2    = Wt1 + 32768;                   // 32,768 h
    float* pooled_parts = (float*)(Wt2 + 32768);    // 32,768 f
    float* invdeg  = pooled_parts + 32768;          // 50,000 f
    int*   gcnt    = (int*)(invdeg + N_NODES);      // 64 i
    // contiguous zero region: degi, cursor, bsum, done
    int*   degi    = gcnt + 64;                     // 50,000 i
    int*   cursor  = degi + N_NODES;                // 50,000 i
    int*   bsum    = cursor + N_NODES;              // 196 i
    int*   done    = bsum + N_SCAN_BLOCKS;          // 1 i
    int*   rowptr  = done + 1;                      // 50,001 i
    int*   eidx    = rowptr + N_NODES + 1;          // 600,000 i

    // 1) prep: zero counters + weight/x fp16 casts
    prep_kernel<<<16 + (N_NODES * 128 / 4 + 255) / 256, 256, 0, stream>>>(
        x, W1l, W1r, W2l, W2r, xh, Wt1, Wt2, degi);

    // 2-4) CSR: degrees -> fused lookback scan -> fill
    deg_kernel<<<(N_EDGES + 255) / 256, 256, 0, stream>>>(dst, degi, N_EDGES);
    scan_fused<<<N_SCAN_BLOCKS, 256, 0, stream>>>(degi, bsum, rowptr, invdeg);
    fill_kernel<<<(N_EDGES + 255) / 256, 256, 0, stream>>>(src, dst, rowptr, cursor, eidx, N_EDGES);

    const int gemm_grid = (N_NODES + GBM - 1) / GBM;   // 782
    const int agg_grid = (N_NODES + 15) / 16;          // 3125

    // 5-6) layer 1
    aggregate_f16<<<agg_grid, 256, 0, stream>>>(xh, rowptr, eidx, invdeg, mean16);
    sage_gemm_f16<<<gemm_grid, 256, 0, stream>>>(mean16, xh, Wt1, b1, h1_16, N_NODES);

    // 7-8) layer 2
    aggregate_f16<<<agg_grid, 256, 0, stream>>>(h1_16, rowptr, eidx, invdeg, mean16);
    sage_gemm_f16<<<gemm_grid, 256, 0, stream>>>(mean16, h1_16, Wt2, b2, h2_16, N_NODES);

    // 9) fused pool + final
    pool_final<<<N_GRAPHS * POOL_PARTS, 256, 0, stream>>>(
        h2_16, batch, Wlin, blin, pooled_parts, gcnt, done, out);
}

// Round 12
// 258.328 us; speedup vs baseline: 2.4479x; 1.2839x over previous
//
#include <hip/hip_runtime.h>
#include <hip/hip_fp16.h>

#define N_NODES 50000
#define N_EDGES 600000
#define N_GRAPHS 64
#define HID 128
#define OUT_C 32

#define N_SCAN_BLOCKS ((N_NODES + 255) / 256)   // 196
#define SCAN_FLAG 0x40000000

typedef __attribute__((ext_vector_type(8))) _Float16 half8;
typedef __attribute__((ext_vector_type(4))) float f32x4;

// ================= prep: zero counters + fp16 casts + graph boundaries =================
// zero region layout (contiguous ints): degi[50000] cursor[50000] bsum[196]
#define ZERO_INTS (2 * N_NODES + N_SCAN_BLOCKS)

__global__ __launch_bounds__(256) void prep_kernel(
    const float* __restrict__ x, const int* __restrict__ batch,
    const float* __restrict__ W1l, const float* __restrict__ W1r,
    const float* __restrict__ W2l, const float* __restrict__ W2r,
    __half* __restrict__ xh, __half* __restrict__ Wt1, __half* __restrict__ Wt2,
    int* __restrict__ zero_base, int* __restrict__ gstart) {
    const int b = blockIdx.x;
    const int t = threadIdx.x;
    const int gtid = b * 256 + t;
    const int gsz = gridDim.x * 256;
    for (int i = gtid; i < ZERO_INTS; i += gsz) zero_base[i] = 0;

    // graph boundaries from sorted batch: gstart[g] = first idx with batch >= g
    for (int i = gtid; i <= N_NODES; i += gsz) {
        if (i == 0) {
            int b1 = batch[0];
            for (int g = 0; g <= b1; ++g) gstart[g] = 0;
        } else if (i == N_NODES) {
            int b0 = batch[N_NODES - 1];
            for (int g = b0 + 1; g <= N_GRAPHS; ++g) gstart[g] = N_NODES;
        } else {
            int b0 = batch[i - 1], b1 = batch[i];
            for (int g = b0 + 1; g <= b1; ++g) gstart[g] = i;
        }
    }

    if (b < 16) {
        for (int i = gtid; i < 65536; i += 4096) {
            int which = i >> 15;                    // 0: layer1, 1: layer2
            int j = i & 32767;
            int n = j >> 8, k = j & 255;
            const float* Wl = which ? W2l : W1l;
            const float* Wr = which ? W2r : W1r;
            float a = (k < 128) ? Wl[n * 128 + k] : Wr[n * 128 + (k - 128)];
            (which ? Wt2 : Wt1)[j] = __float2half(a);
        }
    } else {
        int i = ((b - 16) * 256 + t) * 4;
        if (i < N_NODES * 128) {
            float4 v = *(const float4*)(x + i);
            __half2 a = __floats2half2_rn(v.x, v.y);
            __half2 c = __floats2half2_rn(v.z, v.w);
            uint2 st;
            st.x = *(const unsigned int*)&a;
            st.y = *(const unsigned int*)&c;
            *(uint2*)(xh + i) = st;
        }
    }
}

// ================= CSR: degrees =================
__global__ void deg_kernel(const int* __restrict__ dst, int* __restrict__ deg, int E) {
    int e = blockIdx.x * 256 + threadIdx.x;
    if (e < E) atomicAdd(&deg[dst[e]], 1);
}

// ================= CSR: single-dispatch scan (decoupled lookback) =================
__global__ __launch_bounds__(256) void scan_fused(
    const int* __restrict__ deg, int* __restrict__ bsum,
    int* __restrict__ rowptr, float* __restrict__ invdeg) {
    __shared__ int s[256];
    const int b = blockIdx.x;
    const int t = threadIdx.x;
    const int idx = b * 256 + t;
    const int v = (idx < N_NODES) ? deg[idx] : 0;
    s[t] = v;
    __syncthreads();
    for (int off = 1; off < 256; off <<= 1) {
        int u = (t >= off) ? s[t - off] : 0;
        __syncthreads();
        s[t] += u;
        __syncthreads();
    }
    const int incl = s[t];
    if (t == 255) atomicExch(&bsum[b], incl | SCAN_FLAG);

    int pv = 0;
    if (t < b) {
        int w;
        do { w = atomicAdd(&bsum[t], 0); } while (!(w & SCAN_FLAG));
        pv = w & ~SCAN_FLAG;
    }
    __syncthreads();
    s[t] = pv;
    __syncthreads();
    for (int off = 128; off > 0; off >>= 1) {
        if (t < off) s[t] += s[t + off];
        __syncthreads();
    }
    const int boffs = s[0];

    if (idx < N_NODES) {
        rowptr[idx] = boffs + incl - v;
        invdeg[idx] = 1.0f / fmaxf((float)v, 1.0f);
    }
    if (b == N_SCAN_BLOCKS - 1 && t == 255) rowptr[N_NODES] = boffs + incl;
}

// ================= CSR: fill =================
__global__ void fill_kernel(const int* __restrict__ src, const int* __restrict__ dst,
                            const int* __restrict__ rowptr, int* __restrict__ cursor,
                            int* __restrict__ eidx, int E) {
    int e = blockIdx.x * 256 + threadIdx.x;
    if (e < E) {
        int d = dst[e];
        int pos = atomicAdd(&cursor[d], 1);
        eidx[rowptr[d] + pos] = src[e];
    }
}

// ================= fp16 gather-aggregate: 4 nodes per wave, 16 lanes x 16 B =================
#define AGG8(vv, aa, ab) { aa.x += (float)vv[0]; aa.y += (float)vv[1]; \
                           aa.z += (float)vv[2]; aa.w += (float)vv[3]; \
                           ab.x += (float)vv[4]; ab.y += (float)vv[5]; \
                           ab.z += (float)vv[6]; ab.w += (float)vv[7]; }

__global__ __launch_bounds__(256) void aggregate_f16(
    const __half* __restrict__ feat16, const int* __restrict__ rowptr,
    const int* __restrict__ eidx, const float* __restrict__ invdeg,
    __half* __restrict__ mean16) {
    const int wave = threadIdx.x >> 6;
    const int lane = threadIdx.x & 63;
    const int nh   = lane >> 4;
    const int sub  = lane & 15;
    const int node = blockIdx.x * 16 + wave * 4 + nh;
    const bool act = (node < N_NODES);
    int beg = 0, end = 0;
    if (act) { beg = rowptr[node]; end = rowptr[node + 1]; }
    const size_t coff = (size_t)sub * 8;

    float4 a0 = {0.f,0.f,0.f,0.f}, b0 = {0.f,0.f,0.f,0.f};
    float4 a1 = {0.f,0.f,0.f,0.f}, b1 = {0.f,0.f,0.f,0.f};
    float4 a2 = {0.f,0.f,0.f,0.f}, b2 = {0.f,0.f,0.f,0.f};
    float4 a3 = {0.f,0.f,0.f,0.f}, b3 = {0.f,0.f,0.f,0.f};
    int i = beg;
    for (; i + 8 <= end; i += 8) {
        int s0 = eidx[i+0], s1 = eidx[i+1], s2 = eidx[i+2], s3 = eidx[i+3];
        int s4 = eidx[i+4], s5 = eidx[i+5], s6 = eidx[i+6], s7 = eidx[i+7];
        half8 v0 = *(const half8*)(feat16 + (size_t)s0 * 128 + coff);
        half8 v1 = *(const half8*)(feat16 + (size_t)s1 * 128 + coff);
        half8 v2 = *(const half8*)(feat16 + (size_t)s2 * 128 + coff);
        half8 v3 = *(const half8*)(feat16 + (size_t)s3 * 128 + coff);
        half8 v4 = *(const half8*)(feat16 + (size_t)s4 * 128 + coff);
        half8 v5 = *(const half8*)(feat16 + (size_t)s5 * 128 + coff);
        half8 v6 = *(const half8*)(feat16 + (size_t)s6 * 128 + coff);
        half8 v7 = *(const half8*)(feat16 + (size_t)s7 * 128 + coff);
        AGG8(v0, a0, b0); AGG8(v1, a1, b1); AGG8(v2, a2, b2); AGG8(v3, a3, b3);
        AGG8(v4, a0, b0); AGG8(v5, a1, b1); AGG8(v6, a2, b2); AGG8(v7, a3, b3);
    }
    if (i + 4 <= end) {
        int s0 = eidx[i+0], s1 = eidx[i+1], s2 = eidx[i+2], s3 = eidx[i+3];
        half8 v0 = *(const half8*)(feat16 + (size_t)s0 * 128 + coff);
        half8 v1 = *(const half8*)(feat16 + (size_t)s1 * 128 + coff);
        half8 v2 = *(const half8*)(feat16 + (size_t)s2 * 128 + coff);
        half8 v3 = *(const half8*)(feat16 + (size_t)s3 * 128 + coff);
        AGG8(v0, a0, b0); AGG8(v1, a1, b1); AGG8(v2, a2, b2); AGG8(v3, a3, b3);
        i += 4;
    }
    if (i + 2 <= end) {
        int s0 = eidx[i+0], s1 = eidx[i+1];
        half8 v0 = *(const half8*)(feat16 + (size_t)s0 * 128 + coff);
        half8 v1 = *(const half8*)(feat16 + (size_t)s1 * 128 + coff);
        AGG8(v0, a0, b0); AGG8(v1, a1, b1);
        i += 2;
    }
    if (i < end) {
        int s0 = eidx[i];
        half8 v0 = *(const half8*)(feat16 + (size_t)s0 * 128 + coff);
        AGG8(v0, a0, b0);
    }

    if (act) {
        const float sc = invdeg[node];
        half8 r;
        r[0] = (_Float16)(((a0.x + a1.x) + (a2.x + a3.x)) * sc);
        r[1] = (_Float16)(((a0.y + a1.y) + (a2.y + a3.y)) * sc);
        r[2] = (_Float16)(((a0.z + a1.z) + (a2.z + a3.z)) * sc);
        r[3] = (_Float16)(((a0.w + a1.w) + (a2.w + a3.w)) * sc);
        r[4] = (_Float16)(((b0.x + b1.x) + (b2.x + b3.x)) * sc);
        r[5] = (_Float16)(((b0.y + b1.y) + (b2.y + b3.y)) * sc);
        r[6] = (_Float16)(((b0.z + b1.z) + (b2.z + b3.z)) * sc);
        r[7] = (_Float16)(((b0.w + b1.w) + (b2.w + b3.w)) * sc);
        *(half8*)(mean16 + (size_t)node * 128 + coff) = r;
    }
}

// ================= fp16 MFMA SAGE GEMM (M=50000, N=128, K=256) =================
#define GBM 64
#define BPAD 8

__global__ __launch_bounds__(256) void sage_gemm_f16(
    const __half* __restrict__ mean16, const __half* __restrict__ feat16,
    const __half* __restrict__ Wt, const float* __restrict__ bias,
    __half* __restrict__ out16, int M) {
    __shared__ __align__(16) __half Bs[128][256 + BPAD];

    const int tid = threadIdx.x;
    const int wave = tid >> 6;
    const int lane = tid & 63;
    const int l15 = lane & 15;
    const int quad = lane >> 4;
    const int row0 = blockIdx.x * GBM;
    const int gi_a = min(row0 + wave * 16 + l15, M - 1);

    for (int id = tid; id < 128 * 32; id += 256) {
        int n = id >> 5;
        int kc = (id & 31) * 8;
        *(half8*)&Bs[n][kc] = *(const half8*)(Wt + (size_t)n * 256 + kc);
    }

    half8 af[8];
#pragma unroll
    for (int kb = 0; kb < 8; ++kb) {
        const int k0 = kb * 32;
        const __half* ap = (k0 < 128)
            ? (mean16 + (size_t)gi_a * 128 + k0 + quad * 8)
            : (feat16 + (size_t)gi_a * 128 + (k0 - 128) + quad * 8);
        af[kb] = *(const half8*)ap;
    }

    f32x4 acc[8];
#pragma unroll
    for (int t = 0; t < 8; ++t) acc[t] = (f32x4){0.f, 0.f, 0.f, 0.f};

    __syncthreads();

#pragma unroll
    for (int kb = 0; kb < 8; ++kb) {
#pragma unroll
        for (int t = 0; t < 8; ++t) {
            const half8 b = *(const half8*)&Bs[t * 16 + l15][kb * 32 + quad * 8];
            acc[t] = __builtin_amdgcn_mfma_f32_16x16x32_f16(af[kb], b, acc[t], 0, 0, 0);
        }
    }

#pragma unroll
    for (int r = 0; r < 4; ++r) {
        int gi = row0 + wave * 16 + quad * 4 + r;
        if (gi < M) {
#pragma unroll
            for (int t = 0; t < 8; ++t) {
                int col = t * 16 + l15;
                float v = fmaxf(acc[t][r] + bias[col], 0.f);
                out16[(size_t)gi * 128 + col] = __float2half(v);
            }
        }
    }
}

// ================= pooling: per-part partial sums, boundaries from gstart =================
#define POOL_PARTS 4
__global__ __launch_bounds__(256) void pool_parts(
    const __half* __restrict__ h, const int* __restrict__ gstart,
    float* __restrict__ pooled_parts) {
    const int g = blockIdx.x >> 2;
    const int part = blockIdx.x & 3;
    const int start = gstart[g];
    const int end = gstart[g + 1];

    const int t = threadIdx.x;
    const int c4 = (t & 31) * 4;
    const int rg = t >> 5;
    float4 acc = {0.f, 0.f, 0.f, 0.f};
    for (int n = start + part * 8 + rg; n < end; n += 8 * POOL_PARTS) {
        const __half2* p = (const __half2*)(h + (size_t)n * 128 + c4);
        float2 f0 = __half22float2(p[0]);
        float2 f1 = __half22float2(p[1]);
        acc.x += f0.x; acc.y += f0.y; acc.z += f1.x; acc.w += f1.y;
    }
    __shared__ float sm[8][132];
    sm[rg][c4 + 0] = acc.x;
    sm[rg][c4 + 1] = acc.y;
    sm[rg][c4 + 2] = acc.z;
    sm[rg][c4 + 3] = acc.w;
    __syncthreads();
    if (t < 128) {
        float s = 0.f;
#pragma unroll
        for (int r = 0; r < 8; ++r) s += sm[r][t];
        pooled_parts[(size_t)blockIdx.x * 128 + t] = s;
    }
}

// ================= final linear (R9-proven shape; parts summed inline) =================
__global__ void final_kernel(const float* __restrict__ pooled_parts,
                             const int* __restrict__ gstart,
                             const float* __restrict__ Wlin, const float* __restrict__ blin,
                             float* __restrict__ out) {
    int g = blockIdx.x;
    int j = threadIdx.x;               // 0..31
    float inv = 1.0f / fmaxf((float)(gstart[g + 1] - gstart[g]), 1.0f);
    float sum = blin[j];
    const float* w = Wlin + j * 128;
    const float* p0 = pooled_parts + (size_t)(g * 4 + 0) * 128;
    const float* p1 = pooled_parts + (size_t)(g * 4 + 1) * 128;
    const float* p2 = pooled_parts + (size_t)(g * 4 + 2) * 128;
    const float* p3 = pooled_parts + (size_t)(g * 4 + 3) * 128;
    for (int c = 0; c < 128; ++c) {
        float p = (p0[c] + p1[c]) + (p2[c] + p3[c]);
        sum += p * inv * w[c];
    }
    out[g * 32 + j] = sum;
}

extern "C" void kernel_launch(void* const* d_in, const int* in_sizes, int n_in,
                              void* d_out, int out_size, void* d_ws, size_t ws_size,
                              hipStream_t stream) {
    const float* x    = (const float*)d_in[0];
    const int*   src  = (const int*)d_in[1];
    const int*   dst  = ((const int*)d_in[1]) + N_EDGES;
    const int*   batch= (const int*)d_in[2];
    const float* W1l  = (const float*)d_in[3];
    const float* b1   = (const float*)d_in[4];
    const float* W1r  = (const float*)d_in[5];
    const float* W2l  = (const float*)d_in[6];
    const float* b2   = (const float*)d_in[7];
    const float* W2r  = (const float*)d_in[8];
    const float* Wlin = (const float*)d_in[9];
    const float* blin = (const float*)d_in[10];
    float* out = (float*)d_out;

    __half* xh     = (__half*)d_ws;                 // 6,400,000 h
    __half* mean16 = xh + 6400000;                  // 6,400,000 h
    __half* h1_16  = mean16 + 6400000;              // 6,400,000 h
    __half* h2_16  = h1_16 + 6400000;               // 6,400,000 h
    __half* Wt1    = h2_16 + 6400000;               // 32,768 h
    __half* Wt2    = Wt1 + 32768;                   // 32,768 h
    float* pooled_parts = (float*)(Wt2 + 32768);    // 32,768 f
    float* invdeg  = pooled_parts + 32768;          // 50,000 f
    int*   gstart  = (int*)(invdeg + N_NODES);      // 65 i
    // contiguous zero region: degi, cursor, bsum
    int*   degi    = gstart + 65;                   // 50,000 i
    int*   cursor  = degi + N_NODES;                // 50,000 i
    int*   bsum    = cursor + N_NODES;              // 196 i
    int*   rowptr  = bsum + N_SCAN_BLOCKS;          // 50,001 i
    int*   eidx    = rowptr + N_NODES + 1;          // 600,000 i

    // 1) prep: zero counters + casts + graph boundaries
    prep_kernel<<<16 + (N_NODES * 128 / 4 + 255) / 256, 256, 0, stream>>>(
        x, batch, W1l, W1r, W2l, W2r, xh, Wt1, Wt2, degi, gstart);

    // 2-4) CSR: degrees -> fused lookback scan -> fill
    deg_kernel<<<(N_EDGES + 255) / 256, 256, 0, stream>>>(dst, degi, N_EDGES);
    scan_fused<<<N_SCAN_BLOCKS, 256, 0, stream>>>(degi, bsum, rowptr, invdeg);
    fill_kernel<<<(N_EDGES + 255) / 256, 256, 0, stream>>>(src, dst, rowptr, cursor, eidx, N_EDGES);

    const int gemm_grid = (N_NODES + GBM - 1) / GBM;   // 782
    const int agg_grid = (N_NODES + 15) / 16;          // 3125

    // 5-6) layer 1
    aggregate_f16<<<agg_grid, 256, 0, stream>>>(xh, rowptr, eidx, invdeg, mean16);
    sage_gemm_f16<<<gemm_grid, 256, 0, stream>>>(mean16, xh, Wt1, b1, h1_16, N_NODES);

    // 7-8) layer 2
    aggregate_f16<<<agg_grid, 256, 0, stream>>>(h1_16, rowptr, eidx, invdeg, mean16);
    sage_gemm_f16<<<gemm_grid, 256, 0, stream>>>(mean16, h1_16, Wt2, b2, h2_16, N_NODES);

    // 9-10) pool partials + final linear
    pool_parts<<<N_GRAPHS * POOL_PARTS, 256, 0, stream>>>(h2_16, gstart, pooled_parts);
    final_kernel<<<N_GRAPHS, 32, 0, stream>>>(pooled_parts, gstart, Wlin, blin, out);
}